// Round 3
// baseline (103.814 us; speedup 1.0000x reference)
//
#include <hip/hip_runtime.h>
#include <hip/hip_bf16.h>

// CosSim2D: inputs (32,64,64,64) f32, w (1,576,128) f32, p (128), q (1)
// out (32,64,64,128) f32.
// bf16 MFMA GEMM, implicit im2col from LDS-staged 3-row tile, 1 output row
// per block (2048 blocks -> 5 blocks/CU resident, turnover staggers phases),
// norm fused into staging.

typedef short bf16x8 __attribute__((ext_vector_type(8)));
typedef float f32x4 __attribute__((ext_vector_type(4)));

__device__ __forceinline__ unsigned short f2bf(float f) {
    union { float f; unsigned int u; } v; v.f = f;
    unsigned int u = v.u;
    unsigned int r = (u + 0x7fffu + ((u >> 16) & 1u)) >> 16;  // RNE
    return (unsigned short)r;
}

// ---- pre-kernel: normalize w columns (fp32), store bf16 wn[n][k], k contiguous
__global__ void prep_w_kernel(const float* __restrict__ w,
                              unsigned short* __restrict__ wn) {
    const int n = blockIdx.x;       // 0..127
    const int lane = threadIdx.x;   // 0..63
    float vals[9];
    float s = 0.f;
#pragma unroll
    for (int i = 0; i < 9; ++i) {
        float v = w[(i * 64 + lane) * 128 + n];
        vals[i] = v;
        s += v * v;
    }
#pragma unroll
    for (int off = 1; off < 64; off <<= 1) s += __shfl_xor(s, off);
    const float inv = 1.0f / sqrtf(fmaxf(s, 1e-12f));
#pragma unroll
    for (int i = 0; i < 9; ++i)
        wn[n * 576 + i * 64 + lane] = f2bf(vals[i] * inv);
}

// ---- main: one block = (image b, output row y); 64 pixels x 128 kernels
__global__ __launch_bounds__(256, 5) void cossim_main(
    const float* __restrict__ in, const unsigned short* __restrict__ wn,
    const float* __restrict__ p, const float* __restrict__ q,
    float* __restrict__ out) {
    // A: [3 rows][66 cols (zero-pad 0,65)][72 ch (64 + 16B pad)] bf16 = 28512 B
    __shared__ unsigned short A[3 * 66 * 72];
    __shared__ float rcsum[192];   // per-(row,col) fp32 square-sums
    __shared__ float xni[64];      // per-pixel 1/(||x||+q_eff)
    __shared__ float pfs[128];     // exp(p/P_SCALE)

    const int tid = (int)threadIdx.x;
    // bijective XCD swizzle: 2048 blocks, 8 XCDs, 256 consecutive l per XCD
    const int l = ((int)blockIdx.x & 7) * 256 + ((int)blockIdx.x >> 3);
    const int b = l >> 6, y = l & 63;

    if (tid < 128) pfs[tid] = expf(p[tid] * 0.2f);

    // ---- stage 3 input rows (y-1..y+1) + fused fp32 norm partials
    if (tid < 192) {
        const int r = tid >> 6;        // staged row 0..2
        const int col = tid & 63;
        const int row = y + r - 1;
        unsigned short* dst = &A[(r * 66 + col + 1) * 72];
        float s = 0.f;
        if ((unsigned)row < 64u) {
            const float4* src = reinterpret_cast<const float4*>(
                in + (size_t)b * 262144 + row * 4096 + col * 64);
#pragma unroll
            for (int it = 0; it < 8; ++it) {
                float4 v0 = src[2 * it];
                float4 v1 = src[2 * it + 1];
                s += v0.x * v0.x + v0.y * v0.y + v0.z * v0.z + v0.w * v0.w;
                s += v1.x * v1.x + v1.y * v1.y + v1.z * v1.z + v1.w * v1.w;
                union { float f; unsigned u; } ux, uy, uz, uw;
                uint4 pk;
                ux.f = v0.x; uy.f = v0.y; uz.f = v0.z; uw.f = v0.w;
                pk.x = __builtin_amdgcn_perm(uy.u + 0x8000u, ux.u + 0x8000u, 0x07060302u);
                pk.y = __builtin_amdgcn_perm(uw.u + 0x8000u, uz.u + 0x8000u, 0x07060302u);
                ux.f = v1.x; uy.f = v1.y; uz.f = v1.z; uw.f = v1.w;
                pk.z = __builtin_amdgcn_perm(uy.u + 0x8000u, ux.u + 0x8000u, 0x07060302u);
                pk.w = __builtin_amdgcn_perm(uw.u + 0x8000u, uz.u + 0x8000u, 0x07060302u);
                *reinterpret_cast<uint4*>(dst + it * 8) = pk;
            }
        } else {
            uint4 z; z.x = z.y = z.z = z.w = 0u;
#pragma unroll
            for (int it = 0; it < 8; ++it)
                *reinterpret_cast<uint4*>(dst + it * 8) = z;
        }
        rcsum[tid] = s;
    } else {
        const int t = tid - 192;   // 48 used: 3 rows x 2 sides x 8 chunks
        if (t < 48) {
            const int seg = t >> 3, u = t & 7;
            const int r = seg >> 1, side = seg & 1;
            uint4 z; z.x = z.y = z.z = z.w = 0u;
            *reinterpret_cast<uint4*>(&A[(r * 66 + side * 65) * 72 + u * 8]) = z;
        }
    }
    __syncthreads();

    // ---- per-pixel 1/(||x||+q_eff) from fp32 partials (overlaps MFMA issue)
    if (tid < 64) {
        const float qe = expf(q[0] * (-1.0f / 0.3f));
        const int x = tid;
        float s = 0.f;
#pragma unroll
        for (int dy = 0; dy < 3; ++dy) {
            const float* rs = &rcsum[dy * 64];
            if (x > 0) s += rs[x - 1];
            s += rs[x];
            if (x < 63) s += rs[x + 1];
        }
        xni[tid] = 1.0f / (sqrtf(fmaxf(s, 1e-12f)) + qe);
    }

    // ---- MFMA loop: wave grid 2M x 2N; wave owns 32 pixels x 64 n
    const int wv = tid >> 6, lane = tid & 63;
    const int lr = lane & 15, lg = lane >> 4;
    const int wm = wv >> 1, wnh = wv & 1;
    f32x4 acc[2][4] = {};
    const unsigned short* wb = wn + (wnh * 64 + lr) * 576;

#pragma unroll
    for (int dy = 0; dy < 3; ++dy) {
#pragma unroll
        for (int dx = 0; dx < 3; ++dx) {
            const int tap = dy * 3 + dx;
#pragma unroll
            for (int kc = 0; kc < 2; ++kc) {
                const int kb = tap * 64 + kc * 32 + lg * 8;
                bf16x8 b0 = *reinterpret_cast<const bf16x8*>(wb + kb);
                bf16x8 b1 = *reinterpret_cast<const bf16x8*>(wb + 16 * 576 + kb);
                bf16x8 b2 = *reinterpret_cast<const bf16x8*>(wb + 32 * 576 + kb);
                bf16x8 b3 = *reinterpret_cast<const bf16x8*>(wb + 48 * 576 + kb);
                const unsigned short* abase =
                    &A[(dy * 66 + wm * 32 + lr + dx) * 72 + kc * 32 + lg * 8];
#pragma unroll
                for (int mf = 0; mf < 2; ++mf) {
                    bf16x8 av = *reinterpret_cast<const bf16x8*>(abase + mf * 16 * 72);
                    acc[mf][0] = __builtin_amdgcn_mfma_f32_16x16x32_bf16(av, b0, acc[mf][0], 0, 0, 0);
                    acc[mf][1] = __builtin_amdgcn_mfma_f32_16x16x32_bf16(av, b1, acc[mf][1], 0, 0, 0);
                    acc[mf][2] = __builtin_amdgcn_mfma_f32_16x16x32_bf16(av, b2, acc[mf][2], 0, 0, 0);
                    acc[mf][3] = __builtin_amdgcn_mfma_f32_16x16x32_bf16(av, b3, acc[mf][3], 0, 0, 0);
                }
            }
        }
    }
    __syncthreads();   // xni/pfs visibility before epilogue

    // ---- epilogue: sim = acc * xni; out = sign * (|sim|+eps)^p_eff
    float* orow = out + ((size_t)(b * 64 + y) * 64) * 128;
#pragma unroll
    for (int mf = 0; mf < 2; ++mf) {
#pragma unroll
        for (int i = 0; i < 4; ++i) {
            const int px = wm * 32 + mf * 16 + lg * 4 + i;  // C/D: row=(lane>>4)*4+reg
            const float xn = xni[px];
#pragma unroll
            for (int nf = 0; nf < 4; ++nf) {
                const int n = wnh * 64 + nf * 16 + lr;
                float sim = acc[mf][nf][i] * xn;
                float aa = fabsf(sim) + 1e-6f;
                float r = exp2f(pfs[n] * log2f(aa));
                orow[(size_t)px * 128 + n] = copysignf(r, sim);
            }
        }
    }
}

extern "C" void kernel_launch(void* const* d_in, const int* in_sizes, int n_in,
                              void* d_out, int out_size, void* d_ws, size_t ws_size,
                              hipStream_t stream) {
    (void)in_sizes; (void)n_in; (void)out_size; (void)ws_size;
    const float* in = (const float*)d_in[0];
    const float* w  = (const float*)d_in[1];
    const float* p  = (const float*)d_in[2];
    const float* q  = (const float*)d_in[3];
    float* out = (float*)d_out;
    unsigned short* wn = (unsigned short*)d_ws;  // 128*576 bf16 = 147456 B

    prep_w_kernel<<<128, 64, 0, stream>>>(w, wn);
    cossim_main<<<2048, 256, 0, stream>>>(in, wn, p, q, out);
}

// Round 4
// 45.714 us; speedup vs baseline: 2.2710x; 2.2710x over previous
//
#include <hip/hip_runtime.h>
#include <hip/hip_bf16.h>

// CosSim2D: inputs (32,64,64,64) f32, w (1,576,128) f32, p (128), q (1)
// out (32,64,64,128) f32.
// bf16 MFMA GEMM, implicit im2col from LDS-staged 4-row tile, 2 output rows
// per block (R2 structure: clean 64MB write / 17MB fetch), norm fused into
// staging. R4 change: B repacked fragment-contiguous so each B-load is a
// fully-coalesced 1KB wave access (was 64-line scatter).

typedef short bf16x8 __attribute__((ext_vector_type(8)));
typedef float f32x4 __attribute__((ext_vector_type(4)));

__device__ __forceinline__ unsigned short f2bf(float f) {
    union { float f; unsigned int u; } v; v.f = f;
    unsigned int u = v.u;
    unsigned int r = (u + 0x7fffu + ((u >> 16) & 1u)) >> 16;  // RNE
    return (unsigned short)r;
}

// ---- pre-kernel: normalize w columns (fp32), store bf16 fragment-contiguous:
// wn2[((tap*2 + kc)*128 + n)*32 + koff] = w_hat[k = tap*64 + kc*32 + koff][n]
__global__ void prep_w_kernel(const float* __restrict__ w,
                              unsigned short* __restrict__ wn2) {
    const int n = blockIdx.x;       // 0..127
    const int lane = threadIdx.x;   // 0..63 = k offset within tap
    float vals[9];
    float s = 0.f;
#pragma unroll
    for (int i = 0; i < 9; ++i) {
        float v = w[(i * 64 + lane) * 128 + n];
        vals[i] = v;
        s += v * v;
    }
#pragma unroll
    for (int off = 1; off < 64; off <<= 1) s += __shfl_xor(s, off);
    const float inv = 1.0f / sqrtf(fmaxf(s, 1e-12f));
    const int kc = lane >> 5, koff = lane & 31;
#pragma unroll
    for (int i = 0; i < 9; ++i)
        wn2[((i * 2 + kc) * 128 + n) * 32 + koff] = f2bf(vals[i] * inv);
}

// ---- main: one block = (image b, output rows y0,y0+1); 128 pixels x 128 n
__global__ __launch_bounds__(256, 4) void cossim_main(
    const float* __restrict__ in, const unsigned short* __restrict__ wn,
    const float* __restrict__ p, const float* __restrict__ q,
    float* __restrict__ out) {
    // A: [4 rows][66 cols (zero-pad 0,65)][72 ch (64 + 16B pad)] bf16 = 38016 B
    __shared__ unsigned short A[4 * 66 * 72];
    __shared__ float rcsum[256];   // per-(row,col) fp32 square-sums
    __shared__ float xni[128];     // per-pixel 1/(||x||+q_eff)
    __shared__ float pfs[128];     // exp(p/P_SCALE)

    const int tid = (int)threadIdx.x;
    // bijective XCD swizzle: 1024 blocks, 8 XCDs, 128 consecutive l per XCD
    const int l = ((int)blockIdx.x & 7) * 128 + ((int)blockIdx.x >> 3);
    const int b = l >> 5, y0 = (l & 31) * 2;

    if (tid < 128) pfs[tid] = expf(p[tid] * 0.2f);

    // ---- stage 4 input rows (y0-1 .. y0+2) + fused fp32 norm partials
    {
        const int r = tid >> 6;        // staged row 0..3
        const int col = tid & 63;
        const int row = y0 + r - 1;
        unsigned short* dst = &A[(r * 66 + col + 1) * 72];
        float s = 0.f;
        if ((unsigned)row < 64u) {
            const float4* src = reinterpret_cast<const float4*>(
                in + (size_t)b * 262144 + row * 4096 + col * 64);
#pragma unroll
            for (int it = 0; it < 8; ++it) {
                float4 v0 = src[2 * it];
                float4 v1 = src[2 * it + 1];
                s += v0.x * v0.x + v0.y * v0.y + v0.z * v0.z + v0.w * v0.w;
                s += v1.x * v1.x + v1.y * v1.y + v1.z * v1.z + v1.w * v1.w;
                union { float f; unsigned u; } ux, uy, uz, uw;
                uint4 pk;
                ux.f = v0.x; uy.f = v0.y; uz.f = v0.z; uw.f = v0.w;
                pk.x = __builtin_amdgcn_perm(uy.u + 0x8000u, ux.u + 0x8000u, 0x07060302u);
                pk.y = __builtin_amdgcn_perm(uw.u + 0x8000u, uz.u + 0x8000u, 0x07060302u);
                ux.f = v1.x; uy.f = v1.y; uz.f = v1.z; uw.f = v1.w;
                pk.z = __builtin_amdgcn_perm(uy.u + 0x8000u, ux.u + 0x8000u, 0x07060302u);
                pk.w = __builtin_amdgcn_perm(uw.u + 0x8000u, uz.u + 0x8000u, 0x07060302u);
                *reinterpret_cast<uint4*>(dst + it * 8) = pk;
            }
        } else {
            uint4 z; z.x = z.y = z.z = z.w = 0u;
#pragma unroll
            for (int it = 0; it < 8; ++it)
                *reinterpret_cast<uint4*>(dst + it * 8) = z;
        }
        rcsum[tid] = s;
    }
    if (tid < 64) {  // zero border cols 0 and 65, all 4 rows
        const int r = tid >> 4, side = (tid >> 3) & 1, ch = (tid & 7) * 8;
        uint4 z; z.x = z.y = z.z = z.w = 0u;
        *reinterpret_cast<uint4*>(&A[(r * 66 + side * 65) * 72 + ch]) = z;
    }
    __syncthreads();

    // ---- per-pixel 1/(||x||+q_eff) from fp32 partials (overlaps MFMA issue)
    if (tid < 128) {
        const int ry = tid >> 6, x = tid & 63;
        const float qe = expf(q[0] * (-1.0f / 0.3f));
        float s = 0.f;
#pragma unroll
        for (int dy = 0; dy < 3; ++dy) {
            const float* rs = &rcsum[(ry + dy) * 64];
            if (x > 0) s += rs[x - 1];
            s += rs[x];
            if (x < 63) s += rs[x + 1];
        }
        xni[tid] = 1.0f / (sqrtf(fmaxf(s, 1e-12f)) + qe);
    }

    // ---- MFMA loop: wave grid 2M x 2N; wave owns 64 pixels x 64 n
    const int wv = tid >> 6, lane = tid & 63;
    const int lr = lane & 15, lg = lane >> 4;
    const int wm = wv >> 1, wnh = wv & 1;
    f32x4 acc[4][4] = {};
    // fragment-contiguous B base for this lane: +nf*512 shorts selects nf
    const unsigned short* wB = wn + (wnh * 64 + lr) * 32 + lg * 8;

#pragma unroll
    for (int dy = 0; dy < 3; ++dy) {
#pragma unroll
        for (int dx = 0; dx < 3; ++dx) {
            const int tap = dy * 3 + dx;
#pragma unroll
            for (int kc = 0; kc < 2; ++kc) {
                const unsigned short* wt = wB + (tap * 2 + kc) * 4096;
                bf16x8 b0 = *reinterpret_cast<const bf16x8*>(wt);
                bf16x8 b1 = *reinterpret_cast<const bf16x8*>(wt + 512);
                bf16x8 b2 = *reinterpret_cast<const bf16x8*>(wt + 1024);
                bf16x8 b3 = *reinterpret_cast<const bf16x8*>(wt + 1536);
                const unsigned short* abase =
                    &A[((wm + dy) * 66 + lr + dx) * 72 + kc * 32 + lg * 8];
#pragma unroll
                for (int mf = 0; mf < 4; ++mf) {
                    bf16x8 av = *reinterpret_cast<const bf16x8*>(abase + mf * 16 * 72);
                    acc[mf][0] = __builtin_amdgcn_mfma_f32_16x16x32_bf16(av, b0, acc[mf][0], 0, 0, 0);
                    acc[mf][1] = __builtin_amdgcn_mfma_f32_16x16x32_bf16(av, b1, acc[mf][1], 0, 0, 0);
                    acc[mf][2] = __builtin_amdgcn_mfma_f32_16x16x32_bf16(av, b2, acc[mf][2], 0, 0, 0);
                    acc[mf][3] = __builtin_amdgcn_mfma_f32_16x16x32_bf16(av, b3, acc[mf][3], 0, 0, 0);
                }
            }
        }
    }
    __syncthreads();   // xni/pfs visibility before epilogue

    // ---- epilogue: sim = acc * xni; out = sign * (|sim|+eps)^p_eff
    float* orow = out + ((size_t)(b * 64 + y0 + wm) * 64) * 128;
#pragma unroll
    for (int mf = 0; mf < 4; ++mf) {
#pragma unroll
        for (int i = 0; i < 4; ++i) {
            const int pix = mf * 16 + lg * 4 + i;   // C/D: row=(lane>>4)*4+reg
            const float xn = xni[wm * 64 + pix];
#pragma unroll
            for (int nf = 0; nf < 4; ++nf) {
                const int n = wnh * 64 + nf * 16 + lr;
                float sim = acc[mf][nf][i] * xn;
                float aa = fabsf(sim) + 1e-6f;
                float r = exp2f(pfs[n] * log2f(aa));
                orow[(size_t)pix * 128 + n] = copysignf(r, sim);
            }
        }
    }
}

extern "C" void kernel_launch(void* const* d_in, const int* in_sizes, int n_in,
                              void* d_out, int out_size, void* d_ws, size_t ws_size,
                              hipStream_t stream) {
    (void)in_sizes; (void)n_in; (void)out_size; (void)ws_size;
    const float* in = (const float*)d_in[0];
    const float* w  = (const float*)d_in[1];
    const float* p  = (const float*)d_in[2];
    const float* q  = (const float*)d_in[3];
    float* out = (float*)d_out;
    unsigned short* wn = (unsigned short*)d_ws;  // 18*128*32 bf16 = 147456 B

    prep_w_kernel<<<128, 64, 0, stream>>>(w, wn);
    cossim_main<<<1024, 256, 0, stream>>>(in, wn, p, q, out);
}